// Round 1
// baseline (1071.816 us; speedup 1.0000x reference)
//
#include <hip/hip_runtime.h>
#include <hip/hip_bf16.h>

// GRU (TF GRUCell math), B=2048, T=12, D=512, H=1024, fp32 in/out.
// Strategy: bf16 MFMA (16x16x32) GEMMs, weights pre-packed to B-fragment
// order (LDS-free K-loop), h carried in fp32 + bf16 mirror.
// 2 GEMM kernels per timestep, sequenced on the stream.

#define T_SEQ 12
#define BATCH 2048
#define IND 512
#define HID 1024
#define KTOT (IND + HID)     // 1536
#define KSTEPS (KTOT / 32)   // 48  (x-part = ks 0..15, h-part = ks 16..47)
#define NGATE (2 * HID)      // 2048

typedef __bf16 bf16x8 __attribute__((ext_vector_type(8)));
typedef __bf16 bf16x4 __attribute__((ext_vector_type(4)));
typedef float floatx4 __attribute__((ext_vector_type(4)));

__device__ __forceinline__ float fast_sigmoid(float v) {
  v = fminf(30.f, fmaxf(-30.f, v));
  return 1.f / (1.f + __expf(-v));
}
__device__ __forceinline__ float fast_tanh(float v) {
  v = fminf(15.f, fmaxf(-15.f, v));
  float e = __expf(2.f * v);
  return (e - 1.f) / (e + 1.f);
}

// Pack W [K=1536, N] fp32 row-major -> bf16 in MFMA-B fragment order:
// out[((n_tile*KSTEPS + k_tile)*64 + lane)*8 + j]
//   = W[k_tile*32 + (lane>>4)*8 + j][n_tile*16 + (lane&15)]
// One wave per (n_tile, k_tile); each wave writes 1 KiB contiguous.
__global__ void pack_w(const float* __restrict__ W, __bf16* __restrict__ out, int N) {
  int gid = blockIdx.x * blockDim.x + threadIdx.x;
  int wid = gid >> 6;
  int lane = gid & 63;
  int n_tile = wid / KSTEPS;
  int k_tile = wid - n_tile * KSTEPS;
  int col = n_tile * 16 + (lane & 15);
  int k0 = k_tile * 32 + (lane >> 4) * 8;
  bf16x8 v;
#pragma unroll
  for (int j = 0; j < 8; ++j) v[j] = (__bf16)W[(size_t)(k0 + j) * N + col];
  *reinterpret_cast<bf16x8*>(out + ((size_t)wid * 64 + lane) * 8) = v;
}

__global__ void cvt_bf16(const float4* __restrict__ in, __bf16* __restrict__ out, int n4) {
  int i = blockIdx.x * blockDim.x + threadIdx.x;
  if (i >= n4) return;
  float4 v = in[i];
  bf16x4 o;
  o[0] = (__bf16)v.x; o[1] = (__bf16)v.y; o[2] = (__bf16)v.z; o[3] = (__bf16)v.w;
  *reinterpret_cast<bf16x4*>(out + (size_t)i * 4) = o;
}

__global__ void init_h(const float4* __restrict__ coded, float4* __restrict__ h32,
                       __bf16* __restrict__ hb, int n4) {
  int i = blockIdx.x * blockDim.x + threadIdx.x;
  if (i >= n4) return;
  float4 v = coded[i];
  h32[i] = v;
  bf16x4 o;
  o[0] = (__bf16)v.x; o[1] = (__bf16)v.y; o[2] = (__bf16)v.z; o[3] = (__bf16)v.w;
  *reinterpret_cast<bf16x4*>(hb + (size_t)i * 4) = o;
}

// PHASE 0: gates = sigmoid([xt,h] @ Wg + bg); writes rhb = bf16(r*h), u32 = u.
// PHASE 1: c = tanh([xt,rh] @ Wc + bc); h = u*h + (1-u)*c; writes h32, hb, out[:,t,:].
// Block = 4 waves (2x2), block tile 64(M) x 128(N); wave tile 32x64.
// A-fragment: lane holds A[m0 + lane%16][k0 + (lane/16)*8 .. +7]  (16B vector load)
// B-fragment: packed layout above, lane-contiguous 16B load (no LDS anywhere).
template <int PHASE>
__global__ __launch_bounds__(256) void gru_step(
    const __bf16* __restrict__ Xb,    // [B, T, D] bf16
    const __bf16* __restrict__ Arec,  // phase0: hb [B,H]; phase1: rhb [B,H]
    const __bf16* __restrict__ Wp,    // packed weights
    const float* __restrict__ bias,   // [N]
    float* __restrict__ h32,          // [B,H] fp32 state (phase1 updates)
    __bf16* __restrict__ hb,          // [B,H] bf16 mirror (phase1 writes)
    float* __restrict__ u32,          // [B,H] (phase0 writes, phase1 reads)
    __bf16* __restrict__ rhb,         // [B,H] (phase0 writes)
    float* __restrict__ out,          // [B, T, H]
    int t) {
  const int lane = threadIdx.x & 63;
  const int wave = threadIdx.x >> 6;
  const int quad = lane >> 4;
  const int l16 = lane & 15;
  const int m0 = blockIdx.x * 64 + (wave >> 1) * 32;
  const int n0 = blockIdx.y * 128 + (wave & 1) * 64;

  const __bf16* axp[2];
  const __bf16* ahp[2];
#pragma unroll
  for (int mf = 0; mf < 2; ++mf) {
    int row = m0 + mf * 16 + l16;
    axp[mf] = Xb + ((size_t)row * T_SEQ + t) * IND + quad * 8;
    ahp[mf] = Arec + (size_t)row * HID + quad * 8;
  }
  const __bf16* bp[4];
#pragma unroll
  for (int nf = 0; nf < 4; ++nf)
    bp[nf] = Wp + ((size_t)((n0 >> 4) + nf) * KSTEPS) * 512 + (size_t)lane * 8;

  floatx4 acc[2][4] = {};

  bf16x8 a_cur[2], b_cur[4];
#pragma unroll
  for (int mf = 0; mf < 2; ++mf) a_cur[mf] = *reinterpret_cast<const bf16x8*>(axp[mf]);
#pragma unroll
  for (int nf = 0; nf < 4; ++nf) b_cur[nf] = *reinterpret_cast<const bf16x8*>(bp[nf]);

  for (int ks = 0; ks < KSTEPS; ++ks) {
    bf16x8 a_nxt[2], b_nxt[4];
    const int kn = ks + 1;
    if (kn < KSTEPS) {
#pragma unroll
      for (int mf = 0; mf < 2; ++mf) {
        const __bf16* p = (kn < 16) ? (axp[mf] + kn * 32) : (ahp[mf] + (kn - 16) * 32);
        a_nxt[mf] = *reinterpret_cast<const bf16x8*>(p);
      }
#pragma unroll
      for (int nf = 0; nf < 4; ++nf)
        b_nxt[nf] = *reinterpret_cast<const bf16x8*>(bp[nf] + (size_t)kn * 512);
    }
#pragma unroll
    for (int mf = 0; mf < 2; ++mf)
#pragma unroll
      for (int nf = 0; nf < 4; ++nf)
        acc[mf][nf] = __builtin_amdgcn_mfma_f32_16x16x32_bf16(a_cur[mf], b_cur[nf], acc[mf][nf], 0, 0, 0);
    if (kn < KSTEPS) {
#pragma unroll
      for (int mf = 0; mf < 2; ++mf) a_cur[mf] = a_nxt[mf];
#pragma unroll
      for (int nf = 0; nf < 4; ++nf) b_cur[nf] = b_nxt[nf];
    }
  }

  // Epilogue. C/D layout: col = n0 + nf*16 + (lane&15), row = m0 + mf*16 + quad*4 + i.
#pragma unroll
  for (int mf = 0; mf < 2; ++mf) {
#pragma unroll
    for (int nf = 0; nf < 4; ++nf) {
      int col = n0 + nf * 16 + l16;
      float bv = bias[col];
#pragma unroll
      for (int i = 0; i < 4; ++i) {
        int row = m0 + mf * 16 + quad * 4 + i;
        float v = acc[mf][nf][i] + bv;
        if (PHASE == 0) {
          float s = fast_sigmoid(v);
          if (col < HID) {  // reset gate -> r*h in bf16 for the cand GEMM
            size_t idx = (size_t)row * HID + col;
            rhb[idx] = (__bf16)(s * h32[idx]);
          } else {          // update gate
            u32[(size_t)row * HID + (col - HID)] = s;
          }
        } else {
          float c = fast_tanh(v);
          size_t idx = (size_t)row * HID + col;
          float u = u32[idx];
          float hnew = u * h32[idx] + (1.f - u) * c;
          h32[idx] = hnew;
          hb[idx] = (__bf16)hnew;
          out[((size_t)row * T_SEQ + t) * HID + col] = hnew;
        }
      }
    }
  }
}

extern "C" void kernel_launch(void* const* d_in, const int* in_sizes, int n_in,
                              void* d_out, int out_size, void* d_ws, size_t ws_size,
                              hipStream_t stream) {
  const float* x     = (const float*)d_in[0];
  const float* coded = (const float*)d_in[1];
  const float* Wg_f  = (const float*)d_in[2];
  const float* bg    = (const float*)d_in[3];
  const float* Wc_f  = (const float*)d_in[4];
  const float* bc    = (const float*)d_in[5];
  float* out = (float*)d_out;

  // Workspace carve-up (~60 MB total), 256B aligned slices.
  uintptr_t base = ((uintptr_t)d_ws + 255) & ~(uintptr_t)255;
  auto take = [&](size_t bytes) {
    void* p = (void*)base;
    base = (base + bytes + 255) & ~(uintptr_t)255;
    return p;
  };
  __bf16* Wg  = (__bf16*)take((size_t)(NGATE / 16) * KSTEPS * 512 * 2);  // 6.3 MB
  __bf16* Wc  = (__bf16*)take((size_t)(HID / 16) * KSTEPS * 512 * 2);    // 3.1 MB
  __bf16* Xb  = (__bf16*)take((size_t)BATCH * T_SEQ * IND * 2);          // 25.2 MB
  float*  h32 = (float*) take((size_t)BATCH * HID * 4);                  // 8.4 MB
  __bf16* hb  = (__bf16*)take((size_t)BATCH * HID * 2);                  // 4.2 MB
  float*  u32 = (float*) take((size_t)BATCH * HID * 4);                  // 8.4 MB
  __bf16* rhb = (__bf16*)take((size_t)BATCH * HID * 2);                  // 4.2 MB

  pack_w<<<(NGATE / 16) * KSTEPS * 64 / 256, 256, 0, stream>>>(Wg_f, Wg, NGATE);
  pack_w<<<(HID / 16) * KSTEPS * 64 / 256, 256, 0, stream>>>(Wc_f, Wc, HID);
  cvt_bf16<<<(BATCH * T_SEQ * IND / 4 + 255) / 256, 256, 0, stream>>>(
      (const float4*)x, Xb, BATCH * T_SEQ * IND / 4);
  init_h<<<(BATCH * HID / 4 + 255) / 256, 256, 0, stream>>>(
      (const float4*)coded, (float4*)h32, hb, BATCH * HID / 4);

  for (int t = 0; t < T_SEQ; ++t) {
    gru_step<0><<<dim3(BATCH / 64, NGATE / 128), 256, 0, stream>>>(
        Xb, hb, Wg, bg, h32, hb, u32, rhb, out, t);
    gru_step<1><<<dim3(BATCH / 64, HID / 128), 256, 0, stream>>>(
        Xb, rhb, Wc, bc, h32, hb, u32, rhb, out, t);
  }
}